// Round 1
// baseline (1054.495 us; speedup 1.0000x reference)
//
#include <hip/hip_runtime.h>
#include <math.h>

#define TT 16
#define NN 512
#define FD 5
#define HH 64

__device__ __forceinline__ float sigmoidf_(float x) { return 1.0f / (1.0f + expf(-x)); }
__device__ __forceinline__ float leakyf_(float x)   { return x >= 0.0f ? x : 0.01f * x; }

// ---------------------------------------------------------------------------
// Kernel 1: forward LSTM (16 steps) + backward LSTM (1 step, h0=c0=0 so only
// Wih_b matters) + fc0 + head/tail. 4 sequences per 256-thread block.
// Thread j keeps Whh_f row j (64 floats) in VGPRs; h is LDS-broadcast.
// ---------------------------------------------------------------------------
__global__ __launch_bounds__(256) void k_lstm(
    const float* __restrict__ x,
    const float* __restrict__ Wih_f, const float* __restrict__ Whh_f,
    const float* __restrict__ bih_f, const float* __restrict__ bhh_f,
    const float* __restrict__ Wih_b,
    const float* __restrict__ bih_b, const float* __restrict__ bhh_b,
    const float* __restrict__ fc0_w, const float* __restrict__ fc0_b,
    const float* __restrict__ fc2_w, const float* __restrict__ fc2_b,
    const float* __restrict__ fc3_w, const float* __restrict__ fc3_b,
    float* __restrict__ ws_out, float* __restrict__ ws_head, float* __restrict__ ws_tail)
{
    __shared__ __align__(16) float h_lds[4 * 64];
    __shared__ __align__(16) float gate_lds[4 * 256];
    __shared__ __align__(16) float x_lds[4 * TT * FD];   // 320
    __shared__ __align__(16) float last_lds[4 * 128];

    const int tid  = threadIdx.x;
    const int j    = tid;                 // gate row 0..255
    const int seq0 = blockIdx.x * 4;

    // stage x for the 4 sequences (b = seq>>9, n = seq&511)
    for (int i = tid; i < 4 * TT * FD; i += 256) {
        int s = i / (TT * FD), r = i % (TT * FD);
        int t = r / FD, f = r % FD;
        int seq = seq0 + s;
        int b = seq >> 9, n = seq & 511;
        x_lds[i] = x[(((b * TT) + t) * NN + n) * FD + f];
    }
    h_lds[tid & 255] = 0.0f;   // tid<256 covers all 256 entries
    // recurrent weights into registers (fully unrolled => stays in VGPRs)
    float w[64];
    const float4* W4 = (const float4*)Whh_f;
#pragma unroll
    for (int q = 0; q < 16; ++q) {
        float4 v = W4[j * 16 + q];
        w[4 * q + 0] = v.x; w[4 * q + 1] = v.y; w[4 * q + 2] = v.z; w[4 * q + 3] = v.w;
    }
    float wih[FD];
#pragma unroll
    for (int f = 0; f < FD; ++f) wih[f] = Wih_f[j * FD + f];
    const float bsum = bih_f[j] + bhh_f[j];

    float c = 0.0f;
    __syncthreads();

    for (int t = 0; t < TT; ++t) {
        // phase A: thread j computes gate row j for all 4 sequences
#pragma unroll
        for (int s = 0; s < 4; ++s) {
            float acc = bsum;
#pragma unroll
            for (int q = 0; q < 16; ++q) {
                float4 hv = *(const float4*)&h_lds[s * 64 + q * 4];  // broadcast read
                acc = fmaf(hv.x, w[4 * q + 0], acc);
                acc = fmaf(hv.y, w[4 * q + 1], acc);
                acc = fmaf(hv.z, w[4 * q + 2], acc);
                acc = fmaf(hv.w, w[4 * q + 3], acc);
            }
#pragma unroll
            for (int f = 0; f < FD; ++f)
                acc = fmaf(x_lds[s * (TT * FD) + t * FD + f], wih[f], acc);
            gate_lds[s * 256 + j] = acc;
        }
        __syncthreads();
        // phase B: thread (s,k) updates its cell state; gate order i,f,g,o
        {
            int s = tid >> 6, k = tid & 63;
            float gi = gate_lds[s * 256 + k];
            float gf = gate_lds[s * 256 + 64 + k];
            float gg = gate_lds[s * 256 + 128 + k];
            float go = gate_lds[s * 256 + 192 + k];
            float ii = sigmoidf_(gi), ff = sigmoidf_(gf);
            float gv = tanhf(gg),     oo = sigmoidf_(go);
            c = ff * c + ii * gv;
            h_lds[s * 64 + k] = oo * tanhf(c);
        }
        __syncthreads();
    }

    // backward LSTM: single step on x[t=T-1], zero state (f-gate irrelevant)
    {
        float wb[FD];
#pragma unroll
        for (int f = 0; f < FD; ++f) wb[f] = Wih_b[j * FD + f];
        float bb = bih_b[j] + bhh_b[j];
#pragma unroll
        for (int s = 0; s < 4; ++s) {
            float acc = bb;
#pragma unroll
            for (int f = 0; f < FD; ++f)
                acc = fmaf(x_lds[s * (TT * FD) + (TT - 1) * FD + f], wb[f], acc);
            gate_lds[s * 256 + j] = acc;
        }
    }
    __syncthreads();
    {
        int s = tid >> 6, k = tid & 63;
        float gi = gate_lds[s * 256 + k];
        float gg = gate_lds[s * 256 + 128 + k];
        float go = gate_lds[s * 256 + 192 + k];
        float cb = sigmoidf_(gi) * tanhf(gg);
        float hb = sigmoidf_(go) * tanhf(cb);
        last_lds[s * 128 + k]      = h_lds[s * 64 + k];  // forward final h
        last_lds[s * 128 + 64 + k] = hb;                 // backward first h
    }
    __syncthreads();

    // fc0 + leaky, then head/tail wave reductions (wave == one sequence)
    {
        int s = tid >> 6, k = tid & 63;
        float acc = fc0_b[k];
        const float4* fw4 = (const float4*)fc0_w;
        const float4* l4  = (const float4*)&last_lds[s * 128];
#pragma unroll 8
        for (int q = 0; q < 32; ++q) {
            float4 wv = fw4[k * 32 + q];
            float4 lv = l4[q];
            acc = fmaf(lv.x, wv.x, acc);
            acc = fmaf(lv.y, wv.y, acc);
            acc = fmaf(lv.z, wv.z, acc);
            acc = fmaf(lv.w, wv.w, acc);
        }
        float o = leakyf_(acc);
        int seq = seq0 + s;
        ws_out[seq * 64 + k] = o;

        float ph = o * fc2_w[k];
        float pt = o * fc3_w[k];
#pragma unroll
        for (int m = 32; m >= 1; m >>= 1) {
            ph += __shfl_xor(ph, m);
            pt += __shfl_xor(pt, m);
        }
        if (k == 0) {
            ws_head[seq] = leakyf_(ph + fc2_b[0]);
            ws_tail[seq] = leakyf_(pt + fc3_b[0]);
        }
    }
}

// ---------------------------------------------------------------------------
// Kernel 2: rel_weight = leaky(rel_encoding . fc1_w + fc1_b) at UNMASKED pairs
// only (masked pairs are killed by softmax: exp(-1e9+..) == 0 exactly).
// One wave per 64-pair chunk; ballot; per live pair a coalesced float4 dot.
// ---------------------------------------------------------------------------
__global__ __launch_bounds__(256) void k_rel(
    const float* __restrict__ rel_enc, const float* __restrict__ rel_mask,
    const float* __restrict__ fc1_w, const float* __restrict__ fc1_b,
    float* __restrict__ ws_rel)
{
    const int lane = threadIdx.x & 63;
    const int wave = (int)((blockIdx.x * 256 + threadIdx.x) >> 6);
    const long base = (long)wave * 64;

    float mask = rel_mask[base + lane];
    unsigned long long bal = __ballot(mask > -0.5f);

    float4 fw[4];
#pragma unroll
    for (int q = 0; q < 3; ++q) fw[q] = ((const float4*)fc1_w)[q * 64 + lane];
    if (lane < 14) fw[3] = ((const float4*)fc1_w)[3 * 64 + lane];   // 824 = 768 + 14*4
    const float b0 = fc1_b[0];

    while (bal) {
        int bit = __builtin_ctzll(bal);
        bal &= bal - 1;
        long m = base + bit;
        const float4* r4 = (const float4*)(rel_enc + m * 824);
        float acc = 0.0f;
#pragma unroll
        for (int q = 0; q < 3; ++q) {
            float4 v = r4[q * 64 + lane];
            acc = fmaf(v.x, fw[q].x, acc);
            acc = fmaf(v.y, fw[q].y, acc);
            acc = fmaf(v.z, fw[q].z, acc);
            acc = fmaf(v.w, fw[q].w, acc);
        }
        if (lane < 14) {
            float4 v = r4[3 * 64 + lane];
            acc = fmaf(v.x, fw[3].x, acc);
            acc = fmaf(v.y, fw[3].y, acc);
            acc = fmaf(v.z, fw[3].z, acc);
            acc = fmaf(v.w, fw[3].w, acc);
        }
#pragma unroll
        for (int s = 32; s >= 1; s >>= 1) acc += __shfl_xor(acc, s);
        if (lane == 0) ws_rel[m] = leakyf_(acc + b0);
    }
}

// ---------------------------------------------------------------------------
// Kernel 3: masked softmax over m, propagation, fused prediction.
// One wave per (b,n) row; 4 rows per block.
// ---------------------------------------------------------------------------
__global__ __launch_bounds__(256) void k_prop(
    const float* __restrict__ rel_mask,
    const float* __restrict__ ws_rel,
    const float* __restrict__ ws_out,
    const float* __restrict__ ws_head, const float* __restrict__ ws_tail,
    const float* __restrict__ pred_w, const float* __restrict__ pred_b,
    float* __restrict__ out)
{
    __shared__ float p_lds[4 * 512];
    const int lane = threadIdx.x & 63;
    const int wid  = threadIdx.x >> 6;
    const int row  = blockIdx.x * 4 + wid;      // row = b*512 + n
    const int b = row >> 9, n = row & 511;

    const float hd = ws_head[row];
    float wv[8];
    unsigned okm = 0u;
    float wmax = -INFINITY;
#pragma unroll
    for (int u = 0; u < 8; ++u) {
        int m = lane + 64 * u;
        float msk = rel_mask[n * 512 + m];
        float wgt = 0.0f;
        if (msk > -0.5f) {
            wgt = hd + ws_tail[b * 512 + m] + ws_rel[n * 512 + m];
            wmax = fmaxf(wmax, wgt);
            okm |= 1u << u;
        }
        wv[u] = wgt;
    }
#pragma unroll
    for (int s = 32; s >= 1; s >>= 1) wmax = fmaxf(wmax, __shfl_xor(wmax, s));

    float A = 0.0f;
#pragma unroll
    for (int u = 0; u < 8; ++u) {
        int m = lane + 64 * u;
        float p = 0.0f;
        if (okm & (1u << u)) p = expf(wv[u] - wmax);
        p_lds[wid * 512 + m] = p;
        A += p;
    }
#pragma unroll
    for (int s = 32; s >= 1; s >>= 1) A += __shfl_xor(A, s);
    __syncthreads();

    // lane = hidden index h; accumulate only live m (uniform branch on p)
    float acc = 0.0f;
    for (int m = 0; m < 512; ++m) {
        float p = p_lds[wid * 512 + m];
        if (p != 0.0f)
            acc = fmaf(p, ws_out[(b * 512 + m) * 64 + lane], acc);
    }
    float prop = acc / A;
    float o = ws_out[row * 64 + lane];
    float part = o * pred_w[lane] + prop * pred_w[64 + lane];
#pragma unroll
    for (int s = 32; s >= 1; s >>= 1) part += __shfl_xor(part, s);
    if (lane == 0) out[row] = leakyf_(part + pred_b[0]);
}

// ---------------------------------------------------------------------------
extern "C" void kernel_launch(void* const* d_in, const int* in_sizes, int n_in,
                              void* d_out, int out_size, void* d_ws, size_t ws_size,
                              hipStream_t stream)
{
    const float* x        = (const float*)d_in[0];
    const float* rel_enc  = (const float*)d_in[1];
    const float* rel_mask = (const float*)d_in[2];
    const float* Wih_f = (const float*)d_in[3];
    const float* Whh_f = (const float*)d_in[4];
    const float* bih_f = (const float*)d_in[5];
    const float* bhh_f = (const float*)d_in[6];
    const float* Wih_b = (const float*)d_in[7];
    // d_in[8] = Whh_b: multiplied by h0 == 0 -> unused
    const float* bih_b = (const float*)d_in[9];
    const float* bhh_b = (const float*)d_in[10];
    const float* fc0_w = (const float*)d_in[11];
    const float* fc0_b = (const float*)d_in[12];
    const float* fc1_w = (const float*)d_in[13];
    const float* fc1_b = (const float*)d_in[14];
    const float* fc2_w = (const float*)d_in[15];
    const float* fc2_b = (const float*)d_in[16];
    const float* fc3_w = (const float*)d_in[17];
    const float* fc3_b = (const float*)d_in[18];
    const float* pred_w = (const float*)d_in[19];
    const float* pred_b = (const float*)d_in[20];
    // d_in[21] = all_one: broadcast, implemented directly

    float* ws      = (float*)d_ws;
    float* ws_out  = ws;                       // 2048*64 floats
    float* ws_head = ws_out + 2048 * 64;       // 2048
    float* ws_tail = ws_head + 2048;           // 2048
    float* ws_rel  = ws_tail + 2048;           // 512*512

    k_rel <<<1024, 256, 0, stream>>>(rel_enc, rel_mask, fc1_w, fc1_b, ws_rel);
    k_lstm<<<512,  256, 0, stream>>>(x, Wih_f, Whh_f, bih_f, bhh_f, Wih_b, bih_b, bhh_b,
                                     fc0_w, fc0_b, fc2_w, fc2_b, fc3_w, fc3_b,
                                     ws_out, ws_head, ws_tail);
    k_prop<<<512,  256, 0, stream>>>(rel_mask, ws_rel, ws_out, ws_head, ws_tail,
                                     pred_w, pred_b, (float*)d_out);
}

// Round 2
// 1033.143 us; speedup vs baseline: 1.0207x; 1.0207x over previous
//
#include <hip/hip_runtime.h>
#include <math.h>

#define TT 16
#define NN 512
#define FD 5
#define HH 64

__device__ __forceinline__ float sigmoidf_(float x) { return 1.0f / (1.0f + expf(-x)); }
__device__ __forceinline__ float leakyf_(float x)   { return x >= 0.0f ? x : 0.01f * x; }

// ---------------------------------------------------------------------------
// Kernel FRONT: blocks [0,1024) do the rel_weight sparse scan (memory-bound);
// blocks [1024,1536) do the LSTM pipeline (VALU-bound). No data dependency
// between the two halves, so fusing them into one launch lets the waves
// co-schedule on the CUs (memory latency of rel hidden by LSTM VALU work).
// ---------------------------------------------------------------------------
__global__ __launch_bounds__(256) void k_front(
    // rel inputs
    const float* __restrict__ rel_enc, const float* __restrict__ rel_mask,
    const float* __restrict__ fc1_w, const float* __restrict__ fc1_b,
    float* __restrict__ ws_rel,
    // lstm inputs
    const float* __restrict__ x,
    const float* __restrict__ Wih_f, const float* __restrict__ Whh_f,
    const float* __restrict__ bih_f, const float* __restrict__ bhh_f,
    const float* __restrict__ Wih_b,
    const float* __restrict__ bih_b, const float* __restrict__ bhh_b,
    const float* __restrict__ fc0_w, const float* __restrict__ fc0_b,
    const float* __restrict__ fc2_w, const float* __restrict__ fc2_b,
    const float* __restrict__ fc3_w, const float* __restrict__ fc3_b,
    float* __restrict__ ws_out, float* __restrict__ ws_head, float* __restrict__ ws_tail)
{
    __shared__ __align__(16) float h_lds[4 * 64];
    __shared__ __align__(16) float gate_lds[4 * 256];
    __shared__ __align__(16) float x_lds[4 * TT * FD];   // 320
    __shared__ __align__(16) float last_lds[4 * 128];

    const int tid = threadIdx.x;

    if (blockIdx.x < 1024) {
        // =============== rel path: leaky(rel_enc . fc1_w + b) at live pairs ===
        // Masked pairs are annihilated by the downstream softmax
        // (exp(-1e9 + finite) == 0 exactly), so we skip them entirely.
        const int lane = tid & 63;
        const int wave = (int)((blockIdx.x * 256 + tid) >> 6);
        const long base = (long)wave * 64;

        float mask = rel_mask[base + lane];
        unsigned long long bal = __ballot(mask > -0.5f);

        float4 fw[4];
#pragma unroll
        for (int q = 0; q < 3; ++q) fw[q] = ((const float4*)fc1_w)[q * 64 + lane];
        if (lane < 14) fw[3] = ((const float4*)fc1_w)[3 * 64 + lane];  // 824 = 768 + 14*4
        const float b0 = fc1_b[0];

        while (bal) {
            int bit = __builtin_ctzll(bal);
            bal &= bal - 1;
            long m = base + bit;
            const float4* r4 = (const float4*)(rel_enc + m * 824);
            float acc = 0.0f;
#pragma unroll
            for (int q = 0; q < 3; ++q) {
                float4 v = r4[q * 64 + lane];
                acc = fmaf(v.x, fw[q].x, acc);
                acc = fmaf(v.y, fw[q].y, acc);
                acc = fmaf(v.z, fw[q].z, acc);
                acc = fmaf(v.w, fw[q].w, acc);
            }
            if (lane < 14) {
                float4 v = r4[3 * 64 + lane];
                acc = fmaf(v.x, fw[3].x, acc);
                acc = fmaf(v.y, fw[3].y, acc);
                acc = fmaf(v.z, fw[3].z, acc);
                acc = fmaf(v.w, fw[3].w, acc);
            }
#pragma unroll
            for (int s = 32; s >= 1; s >>= 1) acc += __shfl_xor(acc, s);
            if (lane == 0) ws_rel[m] = leakyf_(acc + b0);
        }
        return;
    }

    // =============== lstm path: fwd 16 steps + bwd 1 step + fc0/head/tail ===
    const int j    = tid;                       // gate row 0..255
    const int seq0 = (blockIdx.x - 1024) * 4;

    for (int i = tid; i < 4 * TT * FD; i += 256) {
        int s = i / (TT * FD), r = i % (TT * FD);
        int t = r / FD, f = r % FD;
        int seq = seq0 + s;
        int b = seq >> 9, n = seq & 511;
        x_lds[i] = x[(((b * TT) + t) * NN + n) * FD + f];
    }
    h_lds[tid & 255] = 0.0f;
    float w[64];
    const float4* W4 = (const float4*)Whh_f;
#pragma unroll
    for (int q = 0; q < 16; ++q) {
        float4 v = W4[j * 16 + q];
        w[4 * q + 0] = v.x; w[4 * q + 1] = v.y; w[4 * q + 2] = v.z; w[4 * q + 3] = v.w;
    }
    float wih[FD];
#pragma unroll
    for (int f = 0; f < FD; ++f) wih[f] = Wih_f[j * FD + f];
    const float bsum = bih_f[j] + bhh_f[j];

    float c = 0.0f;
    __syncthreads();

    for (int t = 0; t < TT; ++t) {
#pragma unroll
        for (int s = 0; s < 4; ++s) {
            float acc = bsum;
#pragma unroll
            for (int q = 0; q < 16; ++q) {
                float4 hv = *(const float4*)&h_lds[s * 64 + q * 4];  // broadcast read
                acc = fmaf(hv.x, w[4 * q + 0], acc);
                acc = fmaf(hv.y, w[4 * q + 1], acc);
                acc = fmaf(hv.z, w[4 * q + 2], acc);
                acc = fmaf(hv.w, w[4 * q + 3], acc);
            }
#pragma unroll
            for (int f = 0; f < FD; ++f)
                acc = fmaf(x_lds[s * (TT * FD) + t * FD + f], wih[f], acc);
            gate_lds[s * 256 + j] = acc;
        }
        __syncthreads();
        {
            int s = tid >> 6, k = tid & 63;
            float gi = gate_lds[s * 256 + k];
            float gf = gate_lds[s * 256 + 64 + k];
            float gg = gate_lds[s * 256 + 128 + k];
            float go = gate_lds[s * 256 + 192 + k];
            float ii = sigmoidf_(gi), ff = sigmoidf_(gf);
            float gv = tanhf(gg),     oo = sigmoidf_(go);
            c = ff * c + ii * gv;
            h_lds[s * 64 + k] = oo * tanhf(c);
        }
        __syncthreads();
    }

    // backward LSTM: single step on x[t=T-1], zero state (Whh_b * 0 drops out)
    {
        float wb[FD];
#pragma unroll
        for (int f = 0; f < FD; ++f) wb[f] = Wih_b[j * FD + f];
        float bb = bih_b[j] + bhh_b[j];
#pragma unroll
        for (int s = 0; s < 4; ++s) {
            float acc = bb;
#pragma unroll
            for (int f = 0; f < FD; ++f)
                acc = fmaf(x_lds[s * (TT * FD) + (TT - 1) * FD + f], wb[f], acc);
            gate_lds[s * 256 + j] = acc;
        }
    }
    __syncthreads();
    {
        int s = tid >> 6, k = tid & 63;
        float gi = gate_lds[s * 256 + k];
        float gg = gate_lds[s * 256 + 128 + k];
        float go = gate_lds[s * 256 + 192 + k];
        float cb = sigmoidf_(gi) * tanhf(gg);
        float hb = sigmoidf_(go) * tanhf(cb);
        last_lds[s * 128 + k]      = h_lds[s * 64 + k];
        last_lds[s * 128 + 64 + k] = hb;
    }
    __syncthreads();

    {
        int s = tid >> 6, k = tid & 63;
        float acc = fc0_b[k];
        const float4* fw4 = (const float4*)fc0_w;
        const float4* l4  = (const float4*)&last_lds[s * 128];
#pragma unroll 8
        for (int q = 0; q < 32; ++q) {
            float4 wv = fw4[k * 32 + q];
            float4 lv = l4[q];
            acc = fmaf(lv.x, wv.x, acc);
            acc = fmaf(lv.y, wv.y, acc);
            acc = fmaf(lv.z, wv.z, acc);
            acc = fmaf(lv.w, wv.w, acc);
        }
        float o = leakyf_(acc);
        int seq = seq0 + s;
        ws_out[seq * 64 + k] = o;

        float ph = o * fc2_w[k];
        float pt = o * fc3_w[k];
#pragma unroll
        for (int m = 32; m >= 1; m >>= 1) {
            ph += __shfl_xor(ph, m);
            pt += __shfl_xor(pt, m);
        }
        if (k == 0) {
            ws_head[seq] = leakyf_(ph + fc2_b[0]);
            ws_tail[seq] = leakyf_(pt + fc3_b[0]);
        }
    }
}

// ---------------------------------------------------------------------------
// Kernel 2: masked softmax + propagation GEMV + fused prediction.
// One wave per (b,n) row; 4 rows per block. Propagation sum is UNCONDITIONAL
// (fmaf(0,x,acc)==acc exactly for finite x -> bit-identical to masked sum)
// so the 512 ws_out loads pipeline instead of sitting behind a branchy
// ds_read-dependent chain.
// ---------------------------------------------------------------------------
__global__ __launch_bounds__(256) void k_prop(
    const float* __restrict__ rel_mask,
    const float* __restrict__ ws_rel,
    const float* __restrict__ ws_out,
    const float* __restrict__ ws_head, const float* __restrict__ ws_tail,
    const float* __restrict__ pred_w, const float* __restrict__ pred_b,
    float* __restrict__ out)
{
    __shared__ float p_lds[4 * 512];
    const int lane = threadIdx.x & 63;
    const int wid  = threadIdx.x >> 6;
    const int row  = blockIdx.x * 4 + wid;      // row = b*512 + n
    const int b = row >> 9, n = row & 511;

    const float hd = ws_head[row];
    float wv[8];
    unsigned okm = 0u;
    float wmax = -INFINITY;
#pragma unroll
    for (int u = 0; u < 8; ++u) {
        int m = lane + 64 * u;
        float msk = rel_mask[n * 512 + m];
        float wgt = 0.0f;
        if (msk > -0.5f) {
            wgt = hd + ws_tail[b * 512 + m] + ws_rel[n * 512 + m];
            wmax = fmaxf(wmax, wgt);
            okm |= 1u << u;
        }
        wv[u] = wgt;
    }
#pragma unroll
    for (int s = 32; s >= 1; s >>= 1) wmax = fmaxf(wmax, __shfl_xor(wmax, s));

    float A = 0.0f;
#pragma unroll
    for (int u = 0; u < 8; ++u) {
        int m = lane + 64 * u;
        float p = 0.0f;
        if (okm & (1u << u)) p = expf(wv[u] - wmax);
        p_lds[wid * 512 + m] = p;
        A += p;
    }
#pragma unroll
    for (int s = 32; s >= 1; s >>= 1) A += __shfl_xor(A, s);
    // p_lds region is wave-private: no __syncthreads needed (compiler inserts
    // the lgkmcnt wait on the RAW dependency).

    // lane = hidden index h: prop[h] = sum_m p[m] * ws_out[b,m,h]
    float acc = 0.0f;
    const float* wsrow = ws_out + ((long)b * 512) * 64 + lane;
    const float* prow  = &p_lds[wid * 512];
#pragma unroll 8
    for (int m = 0; m < 512; ++m)
        acc = fmaf(prow[m], wsrow[(long)m * 64], acc);

    float prop = acc / A;
    float o = ws_out[(long)row * 64 + lane];
    float part = o * pred_w[lane] + prop * pred_w[64 + lane];
#pragma unroll
    for (int s = 32; s >= 1; s >>= 1) part += __shfl_xor(part, s);
    if (lane == 0) out[row] = leakyf_(part + pred_b[0]);
}

// ---------------------------------------------------------------------------
extern "C" void kernel_launch(void* const* d_in, const int* in_sizes, int n_in,
                              void* d_out, int out_size, void* d_ws, size_t ws_size,
                              hipStream_t stream)
{
    const float* x        = (const float*)d_in[0];
    const float* rel_enc  = (const float*)d_in[1];
    const float* rel_mask = (const float*)d_in[2];
    const float* Wih_f = (const float*)d_in[3];
    const float* Whh_f = (const float*)d_in[4];
    const float* bih_f = (const float*)d_in[5];
    const float* bhh_f = (const float*)d_in[6];
    const float* Wih_b = (const float*)d_in[7];
    // d_in[8] = Whh_b: multiplied by h0 == 0 -> unused
    const float* bih_b = (const float*)d_in[9];
    const float* bhh_b = (const float*)d_in[10];
    const float* fc0_w = (const float*)d_in[11];
    const float* fc0_b = (const float*)d_in[12];
    const float* fc1_w = (const float*)d_in[13];
    const float* fc1_b = (const float*)d_in[14];
    const float* fc2_w = (const float*)d_in[15];
    const float* fc2_b = (const float*)d_in[16];
    const float* fc3_w = (const float*)d_in[17];
    const float* fc3_b = (const float*)d_in[18];
    const float* pred_w = (const float*)d_in[19];
    const float* pred_b = (const float*)d_in[20];
    // d_in[21] = all_one: broadcast of ones, implemented implicitly

    float* ws      = (float*)d_ws;
    float* ws_out  = ws;                       // 2048*64 floats
    float* ws_head = ws_out + 2048 * 64;       // 2048
    float* ws_tail = ws_head + 2048;           // 2048
    float* ws_rel  = ws_tail + 2048;           // 512*512

    k_front<<<1536, 256, 0, stream>>>(rel_enc, rel_mask, fc1_w, fc1_b, ws_rel,
                                      x, Wih_f, Whh_f, bih_f, bhh_f, Wih_b, bih_b, bhh_b,
                                      fc0_w, fc0_b, fc2_w, fc2_b, fc3_w, fc3_b,
                                      ws_out, ws_head, ws_tail);
    k_prop <<<512, 256, 0, stream>>>(rel_mask, ws_rel, ws_out, ws_head, ws_tail,
                                     pred_w, pred_b, (float*)d_out);
}